// Round 11
// baseline (81.994 us; speedup 1.0000x reference)
//
#include <hip/hip_runtime.h>

typedef _Float16 half8 __attribute__((ext_vector_type(8)));
typedef float f32x16 __attribute__((ext_vector_type(16)));

#define NPTS   4096
#define BATCH  16
#define BLOCK  256
#define CHUNK  2048      // others staged per LDS pass (32 KB)
#define NCHUNK 2
#define NBLK   1024      // 2 dir x 16 batch x 32 self-tiles(128)

// dist(s,o) = |s|^2 + (s.g + q), g = -2o, q = |o|^2, f16 hi/lo split.
// One 16-B record per other: R = [ghx,ghy,ghz,glx,gly,glz,qh,ql].
// Both K-groups read the SAME record; the A-fragment differs per group:
//   grp0: A=[shx,shy,shz, 0,0,0, 1, 0]       -> sh.gh + qh
//   grp1: A=[slx,sly,slz, shx,shy,shz, 0, 1] -> sl.gh + sh.gl + ql
// (verified exact vs harness: R9/R10 absmax 0.0)
// R11: 4 blocks/CU; per block 128 selves; wave = 64 selves x half the others
// (sg = wv&1 selects selves, oh = wv>>1 selects others half). Cross-wave
// combine merges the two halves before the epilogue.
__global__ __launch_bounds__(BLOCK, 4) void chamfer_mfma_kernel(
    const float* __restrict__ p1, const float* __restrict__ p2,
    float* __restrict__ partial)
{
    __shared__ half8 REC[CHUNK];    // 32 KB; reused for combine after loop

    const int tid  = threadIdx.x;
    const int lane = tid & 63;
    const int n    = lane & 31;     // tile col (other) / A row (self)
    const int grp  = lane >> 5;     // K-group
    const int wv   = tid >> 6;
    const int sg   = wv & 1;        // self group (64 selves)
    const int oh   = wv >> 1;       // others half (2048 others)
    const int blk  = blockIdx.x;    // 0..1023 (exactly 4 blocks/CU)
    const int j    = blk & 31;      // self tile of 128
    const int b    = (blk >> 5) & 15;
    const int dir  = blk >> 9;

    const float* selfp  = (dir == 0 ? p1 : p2) + (size_t)b * NPTS * 3;
    const float* otherp = (dir == 0 ? p2 : p1) + (size_t)b * NPTS * 3;

    // ---- Two A fragments: selves s0 = base+n and s1 = base+32+n ----
    const int base = j * 128 + sg * 64;
    half8 a0, a1;
    float ssq01;
    {
        const int i0 = (base + n) * 3, i1 = (base + 32 + n) * 3;
        float x0 = selfp[i0], y0 = selfp[i0 + 1], z0 = selfp[i0 + 2];
        float x1 = selfp[i1], y1 = selfp[i1 + 1], z1 = selfp[i1 + 2];
        ssq01 = fmaf(x0, x0, fmaf(y0, y0, z0 * z0)) +
                fmaf(x1, x1, fmaf(y1, y1, z1 * z1));
        _Float16 hx0 = (_Float16)x0, hy0 = (_Float16)y0, hz0 = (_Float16)z0;
        _Float16 lx0 = (_Float16)(x0 - (float)hx0);
        _Float16 ly0 = (_Float16)(y0 - (float)hy0);
        _Float16 lz0 = (_Float16)(z0 - (float)hz0);
        _Float16 hx1 = (_Float16)x1, hy1 = (_Float16)y1, hz1 = (_Float16)z1;
        _Float16 lx1 = (_Float16)(x1 - (float)hx1);
        _Float16 ly1 = (_Float16)(y1 - (float)hy1);
        _Float16 lz1 = (_Float16)(z1 - (float)hz1);
        const _Float16 c0 = (_Float16)0.f, c1 = (_Float16)1.f;
        if (grp == 0) {
            a0[0]=hx0; a0[1]=hy0; a0[2]=hz0; a0[3]=c0; a0[4]=c0; a0[5]=c0; a0[6]=c1; a0[7]=c0;
            a1[0]=hx1; a1[1]=hy1; a1[2]=hz1; a1[3]=c0; a1[4]=c0; a1[5]=c0; a1[6]=c1; a1[7]=c0;
        } else {
            a0[0]=lx0; a0[1]=ly0; a0[2]=lz0; a0[3]=hx0; a0[4]=hy0; a0[5]=hz0; a0[6]=c0; a0[7]=c1;
            a1[0]=lx1; a1[1]=ly1; a1[2]=lz1; a1[3]=hx1; a1[4]=hy1; a1[5]=hz1; a1[6]=c0; a1[7]=c1;
        }
    }

    f32x16 m0, m1, zc;
#pragma unroll
    for (int r = 0; r < 16; ++r) { m0[r] = 3.4e38f; m1[r] = 3.4e38f; zc[r] = 0.f; }

    for (int c = 0; c < NCHUNK; ++c) {
        __syncthreads();
        {   // Stage 8 others/thread: R-records, contiguous b128 writes.
            const float4* src = (const float4*)(otherp + (size_t)c * CHUNK * 3);
            float4 v0 = src[tid * 6 + 0], v1 = src[tid * 6 + 1];
            float4 v2 = src[tid * 6 + 2], v3 = src[tid * 6 + 3];
            float4 v4 = src[tid * 6 + 4], v5 = src[tid * 6 + 5];
            float ox[8] = {v0.x, v0.w, v1.z, v2.y, v3.x, v3.w, v4.z, v5.y};
            float oy[8] = {v0.y, v1.x, v1.w, v2.z, v3.y, v4.x, v4.w, v5.z};
            float oz[8] = {v0.z, v1.y, v2.x, v2.w, v3.z, v4.y, v5.x, v5.w};
#pragma unroll
            for (int k = 0; k < 8; ++k) {
                float gx = -2.f * ox[k], gy = -2.f * oy[k], gz = -2.f * oz[k];
                float q  = fmaf(ox[k], ox[k], fmaf(oy[k], oy[k], oz[k] * oz[k]));
                _Float16 ghx = (_Float16)gx, ghy = (_Float16)gy, ghz = (_Float16)gz;
                half8 r;
                r[0] = ghx; r[1] = ghy; r[2] = ghz;
                r[3] = (_Float16)(gx - (float)ghx);
                r[4] = (_Float16)(gy - (float)ghy);
                r[5] = (_Float16)(gz - (float)ghz);
                _Float16 qh = (_Float16)q;
                r[6] = qh;
                r[7] = (_Float16)(q - (float)qh);
                REC[tid * 8 + k] = r;
            }
        }
        __syncthreads();
        // This wave's half: 32 tiles of 32 others; 2 B-reads x 2 A = 4 MFMAs.
        const half8* rp = REC + oh * (CHUNK / 2) + n;
#pragma unroll 2
        for (int g = 0; g < CHUNK / 2 / 64; ++g) {      // 16 iters
            half8 b0 = rp[g * 64];
            half8 b1 = rp[g * 64 + 32];
            f32x16 o00 = __builtin_amdgcn_mfma_f32_32x32x16_f16(a0, b0, zc, 0, 0, 0);
            f32x16 o01 = __builtin_amdgcn_mfma_f32_32x32x16_f16(a0, b1, zc, 0, 0, 0);
            f32x16 o10 = __builtin_amdgcn_mfma_f32_32x32x16_f16(a1, b0, zc, 0, 0, 0);
            f32x16 o11 = __builtin_amdgcn_mfma_f32_32x32x16_f16(a1, b1, zc, 0, 0, 0);
#pragma unroll
            for (int r = 0; r < 16; ++r) {
                m0[r] = fminf(fminf(o00[r], o01[r]), m0[r]);   // v_min3_f32
                m1[r] = fminf(fminf(o10[r], o11[r]), m1[r]);
            }
        }
    }

    // ---- Cross-wave combine: min the two others-halves (same sg) ----
    __syncthreads();
    float* CW = (float*)REC;        // [sg][tile][lane] stride 17: conflict-free
    if (oh == 1) {
#pragma unroll
        for (int r = 0; r < 16; ++r) {
            CW[((sg * 2 + 0) * 64 + lane) * 17 + r] = m0[r];
            CW[((sg * 2 + 1) * 64 + lane) * 17 + r] = m1[r];
        }
    }
    __syncthreads();
    if (oh == 0) {
#pragma unroll
        for (int r = 0; r < 16; ++r) {
            m0[r] = fminf(m0[r], CW[((sg * 2 + 0) * 64 + lane) * 17 + r]);
            m1[r] = fminf(m1[r], CW[((sg * 2 + 1) * 64 + lane) * 17 + r]);
        }
        // ---- Epilogue (verified in R10): col-min, rowsum, ssq ----
#pragma unroll
        for (int mask = 1; mask <= 16; mask <<= 1) {
#pragma unroll
            for (int r = 0; r < 16; ++r) {
                m0[r] = fminf(m0[r], __shfl_xor((float)m0[r], mask, 64));
                m1[r] = fminf(m1[r], __shfl_xor((float)m1[r], mask, 64));
            }
        }
        float rowsum = 0.f;
#pragma unroll
        for (int r = 0; r < 16; ++r) rowsum += m0[r] + m1[r];
        rowsum += __shfl_xor(rowsum, 32, 64);   // other K-group's rows

        float sv = grp ? 0.f : ssq01;           // each self counted once
#pragma unroll
        for (int mask = 1; mask <= 16; mask <<= 1)
            sv += __shfl_xor(sv, mask, 64);

        if (lane == 0) partial[blk * 2 + sg] = rowsum + sv;   // plain store
    }
}

__global__ __launch_bounds__(256) void chamfer_reduce(
    const float* __restrict__ partial, float* __restrict__ out)
{
    float s = 0.f;
    for (int i = threadIdx.x; i < NBLK * 2; i += 256) s += partial[i];
#pragma unroll
    for (int off = 32; off > 0; off >>= 1) s += __shfl_down(s, off, 64);
    __shared__ float ws4[4];
    int lane = threadIdx.x & 63, wv = threadIdx.x >> 6;
    if (lane == 0) ws4[wv] = s;
    __syncthreads();
    if (threadIdx.x == 0)
        out[0] = (ws4[0] + ws4[1] + ws4[2] + ws4[3]) * (1.0f / BATCH);
}

extern "C" void kernel_launch(void* const* d_in, const int* in_sizes, int n_in,
                              void* d_out, int out_size, void* d_ws, size_t ws_size,
                              hipStream_t stream) {
    const float* p1 = (const float*)d_in[0];
    const float* p2 = (const float*)d_in[1];
    float* out = (float*)d_out;
    float* partial = (float*)d_ws;   // 2048 floats; fully overwritten each call

    chamfer_mfma_kernel<<<dim3(NBLK), dim3(BLOCK), 0, stream>>>(p1, p2, partial);
    chamfer_reduce<<<dim3(1), dim3(256), 0, stream>>>(partial, out);
}

// Round 12
// 79.634 us; speedup vs baseline: 1.0296x; 1.0296x over previous
//
#include <hip/hip_runtime.h>

typedef _Float16 half8 __attribute__((ext_vector_type(8)));
typedef float f32x16 __attribute__((ext_vector_type(16)));

#define NPTS   4096
#define BATCH  16
#define BLOCK  512       // 8 waves
#define CHUNK  4096      // ALL others staged once (64 KB)
#define NBLK   512       // 2 dir x 16 batch x 16 self-tiles(256) = 2 blocks/CU

// dist(s,o) = |s|^2 + (s.g + q), g = -2o, q = |o|^2, f16 hi/lo split.
// 16-B record/other: R = [ghx,ghy,ghz,glx,gly,glz,qh,ql]. A-frag per K-group:
//   grp0: A=[shx,shy,shz, 0,0,0, 1, 0]       -> sh.gh + qh
//   grp1: A=[slx,sly,slz, shx,shy,shz, 0, 1] -> sl.gh + sh.gl + ql
// (verified exact: R9/R10/R11 absmax 0.0)
// R12 partition: block = 256 selves; wave = 64 selves (2 A-frags) x half the
// others (oh). 2 blocks/CU -> 4 waves/SIMD; 2-MFMA batches keep VGPR <= 128.
__global__ __launch_bounds__(BLOCK, 4) void chamfer_mfma_kernel(
    const float* __restrict__ p1, const float* __restrict__ p2,
    float* __restrict__ partial)
{
    __shared__ half8 REC[CHUNK];    // 64 KB; combine area reuses it after loop

    const int tid  = threadIdx.x;
    const int lane = tid & 63;
    const int n    = lane & 31;     // tile col (other) / A row (self)
    const int grp  = lane >> 5;     // K-group
    const int wv   = tid >> 6;      // 0..7
    const int sg   = wv & 3;        // self group: 64 selves each
    const int oh   = wv >> 2;       // others half: 2048 others each
    const int blk  = blockIdx.x;
    const int j    = blk & 15;      // self tile of 256
    const int b    = (blk >> 4) & 15;
    const int dir  = blk >> 8;

    const float* selfp  = (dir == 0 ? p1 : p2) + (size_t)b * NPTS * 3;
    const float* otherp = (dir == 0 ? p2 : p1) + (size_t)b * NPTS * 3;

    // ---- Two A fragments: selves s0 = base+n, s1 = base+32+n ----
    const int base = j * 256 + sg * 64;
    half8 a0, a1;
    float ssq01;
    {
        const int i0 = (base + n) * 3, i1 = (base + 32 + n) * 3;
        float x0 = selfp[i0], y0 = selfp[i0 + 1], z0 = selfp[i0 + 2];
        float x1 = selfp[i1], y1 = selfp[i1 + 1], z1 = selfp[i1 + 2];
        ssq01 = fmaf(x0, x0, fmaf(y0, y0, z0 * z0)) +
                fmaf(x1, x1, fmaf(y1, y1, z1 * z1));
        _Float16 hx0 = (_Float16)x0, hy0 = (_Float16)y0, hz0 = (_Float16)z0;
        _Float16 hx1 = (_Float16)x1, hy1 = (_Float16)y1, hz1 = (_Float16)z1;
        const _Float16 c0 = (_Float16)0.f, c1 = (_Float16)1.f;
        if (grp == 0) {
            a0[0]=hx0; a0[1]=hy0; a0[2]=hz0; a0[3]=c0; a0[4]=c0; a0[5]=c0; a0[6]=c1; a0[7]=c0;
            a1[0]=hx1; a1[1]=hy1; a1[2]=hz1; a1[3]=c0; a1[4]=c0; a1[5]=c0; a1[6]=c1; a1[7]=c0;
        } else {
            a0[0]=(_Float16)(x0-(float)hx0); a0[1]=(_Float16)(y0-(float)hy0);
            a0[2]=(_Float16)(z0-(float)hz0); a0[3]=hx0; a0[4]=hy0; a0[5]=hz0;
            a0[6]=c0; a0[7]=c1;
            a1[0]=(_Float16)(x1-(float)hx1); a1[1]=(_Float16)(y1-(float)hy1);
            a1[2]=(_Float16)(z1-(float)hz1); a1[3]=hx1; a1[4]=hy1; a1[5]=hz1;
            a1[6]=c0; a1[7]=c1;
        }
    }

    // ---- Stage all 4096 others: 512 threads x 8 records ----
    {
        const float4* src = (const float4*)otherp;
        float4 v0 = src[tid * 6 + 0], v1 = src[tid * 6 + 1];
        float4 v2 = src[tid * 6 + 2], v3 = src[tid * 6 + 3];
        float4 v4 = src[tid * 6 + 4], v5 = src[tid * 6 + 5];
        float ox[8] = {v0.x, v0.w, v1.z, v2.y, v3.x, v3.w, v4.z, v5.y};
        float oy[8] = {v0.y, v1.x, v1.w, v2.z, v3.y, v4.x, v4.w, v5.z};
        float oz[8] = {v0.z, v1.y, v2.x, v2.w, v3.z, v4.y, v5.x, v5.w};
#pragma unroll
        for (int k = 0; k < 8; ++k) {
            float gx = -2.f * ox[k], gy = -2.f * oy[k], gz = -2.f * oz[k];
            float q  = fmaf(ox[k], ox[k], fmaf(oy[k], oy[k], oz[k] * oz[k]));
            _Float16 ghx = (_Float16)gx, ghy = (_Float16)gy, ghz = (_Float16)gz;
            half8 r;
            r[0] = ghx; r[1] = ghy; r[2] = ghz;
            r[3] = (_Float16)(gx - (float)ghx);
            r[4] = (_Float16)(gy - (float)ghy);
            r[5] = (_Float16)(gz - (float)ghz);
            _Float16 qh = (_Float16)q;
            r[6] = qh;
            r[7] = (_Float16)(q - (float)qh);
            REC[tid * 8 + k] = r;
        }
    }
    __syncthreads();

    f32x16 m0, m1, zc;
#pragma unroll
    for (int r = 0; r < 16; ++r) { m0[r] = 3.4e38f; m1[r] = 3.4e38f; zc[r] = 0.f; }

    // ---- Main loop: this wave's 2048-other half, 64 tiles of 32 ----
    const half8* rp = REC + oh * 2048 + n;
#pragma unroll 2
    for (int g = 0; g < 64; ++g) {
        half8 bf = rp[g * 32];
        f32x16 o0 = __builtin_amdgcn_mfma_f32_32x32x16_f16(a0, bf, zc, 0, 0, 0);
        f32x16 o1 = __builtin_amdgcn_mfma_f32_32x32x16_f16(a1, bf, zc, 0, 0, 0);
#pragma unroll
        for (int r = 0; r < 16; ++r) {
            m0[r] = fminf(m0[r], o0[r]);
            m1[r] = fminf(m1[r], o1[r]);
        }
    }

    // ---- Cross-wave combine: min the two others-halves (same sg) ----
    __syncthreads();
    float* CW = (float*)REC;        // (sg*64+lane)*33 + r : stride-33, r<32
    if (oh == 1) {
#pragma unroll
        for (int r = 0; r < 16; ++r) {
            CW[(sg * 64 + lane) * 33 + r]      = m0[r];
            CW[(sg * 64 + lane) * 33 + 16 + r] = m1[r];
        }
    }
    __syncthreads();
    if (oh == 0) {
#pragma unroll
        for (int r = 0; r < 16; ++r) {
            m0[r] = fminf(m0[r], CW[(sg * 64 + lane) * 33 + r]);
            m1[r] = fminf(m1[r], CW[(sg * 64 + lane) * 33 + 16 + r]);
        }
        // ---- Epilogue (verified R10): col-min tree, rowsum, ssq ----
#pragma unroll
        for (int mask = 1; mask <= 16; mask <<= 1) {
#pragma unroll
            for (int r = 0; r < 16; ++r) {
                m0[r] = fminf(m0[r], __shfl_xor((float)m0[r], mask, 64));
                m1[r] = fminf(m1[r], __shfl_xor((float)m1[r], mask, 64));
            }
        }
        float rowsum = 0.f;
#pragma unroll
        for (int r = 0; r < 16; ++r) rowsum += m0[r] + m1[r];
        rowsum += __shfl_xor(rowsum, 32, 64);   // other K-group's rows

        float sv = grp ? 0.f : ssq01;           // each self counted once
#pragma unroll
        for (int mask = 1; mask <= 16; mask <<= 1)
            sv += __shfl_xor(sv, mask, 64);

        if (lane == 0) partial[blk * 4 + sg] = rowsum + sv;   // plain store
    }
}

__global__ __launch_bounds__(256) void chamfer_reduce(
    const float* __restrict__ partial, float* __restrict__ out)
{
    float s = 0.f;
    for (int i = threadIdx.x; i < NBLK * 4; i += 256) s += partial[i];
#pragma unroll
    for (int off = 32; off > 0; off >>= 1) s += __shfl_down(s, off, 64);
    __shared__ float ws4[4];
    int lane = threadIdx.x & 63, wv = threadIdx.x >> 6;
    if (lane == 0) ws4[wv] = s;
    __syncthreads();
    if (threadIdx.x == 0)
        out[0] = (ws4[0] + ws4[1] + ws4[2] + ws4[3]) * (1.0f / BATCH);
}

extern "C" void kernel_launch(void* const* d_in, const int* in_sizes, int n_in,
                              void* d_out, int out_size, void* d_ws, size_t ws_size,
                              hipStream_t stream) {
    const float* p1 = (const float*)d_in[0];
    const float* p2 = (const float*)d_in[1];
    float* out = (float*)d_out;
    float* partial = (float*)d_ws;   // 2048 floats; fully overwritten each call

    chamfer_mfma_kernel<<<dim3(NBLK), dim3(BLOCK), 0, stream>>>(p1, p2, partial);
    chamfer_reduce<<<dim3(1), dim3(256), 0, stream>>>(partial, out);
}